// Round 5
// baseline (8082.902 us; speedup 1.0000x reference)
//
#include <hip/hip_runtime.h>
#include <hip/hip_fp16.h>

typedef _Float16 half8 __attribute__((ext_vector_type(8)));
typedef _Float16 half4v __attribute__((ext_vector_type(4)));
typedef float floatx4 __attribute__((ext_vector_type(4)));

#define T_    128
#define B_    64
#define HCH   128        // hidden channels
#define NQ    4608       // 128 ch * 36 (cols: n = ch*36 + p*4 + g ; p=0..8 pos, g=0..3 gate i,f,o,g)
#define KH    1152       // HCH*9
#define NROWS 8192       // B_*T_

__device__ __forceinline__ float sigm(float x){ return 1.0f/(1.0f + __expf(-x)); }

__device__ __forceinline__ void gll16(const _Float16* g, const _Float16* l){
  __builtin_amdgcn_global_load_lds(
      (const __attribute__((address_space(1))) unsigned int*)g,
      (__attribute__((address_space(3))) unsigned int*)l, 16, 0, 0);
}

// ---------- pack: fp32 -> fp16 cast (vectorized x4) ----------
__global__ void k_cast_f16(const float* __restrict__ src, _Float16* __restrict__ dst, int n4){
  int i = blockIdx.x*blockDim.x + threadIdx.x;
  if (i >= n4) return;
  float4 v = ((const float4*)src)[i];
  half4v h;
  h[0] = (_Float16)v.x; h[1] = (_Float16)v.y; h[2] = (_Float16)v.z; h[3] = (_Float16)v.w;
  ((half4v*)dst)[i] = h;
}

// ---------- pack conv weights -> dense W2^T [N][K]; col n = ch*36 + p*4 + g ----------
// w: [4H][Cx+128][3][3].  Wx: [4608][Cx*9].  Wh: [4620][1152] (rows 4608..4619 zero).
__global__ void k_pack_w2(const float* __restrict__ w, _Float16* __restrict__ Wx,
                          _Float16* __restrict__ Wh, int Cx, int total){
  int idx = blockIdx.x*256 + threadIdx.x;
  if (idx >= total) return;
  int Kx = Cx*9;
  int nWx = NQ*Kx;
  int n, kk, ci;
  _Float16* dst;
  bool pad = false;
  if (idx < nWx) { n = idx / Kx; kk = idx % Kx; ci = kk/9; dst = Wx + idx; }
  else {
    int e = idx - nWx;
    n = e / KH; kk = e % KH; ci = Cx + kk/9; dst = Wh + e;
    pad = (n >= NQ);
  }
  float val = 0.0f;
  if (!pad) {
    int ch = n/36, r = n%36, p = r>>2, g = r&3, q = kk%9;
    int kr = q/3 - p/3 + 1, kc = q%3 - p%3 + 1;
    if (kr>=0 && kr<3 && kc>=0 && kc<3)
      val = w[(((g*HCH+ch)*(Cx+HCH) + ci)*3 + kr)*3 + kc];
  }
  *dst = (_Float16)val;
}

// ---------- pack biases into interleaved order: [4][4608] ----------
__global__ void k_pack_bias(const float* __restrict__ b0f, const float* __restrict__ b0b,
                            const float* __restrict__ b1f, const float* __restrict__ b1b,
                            float* __restrict__ outb){
  int idx = blockIdx.x*256 + threadIdx.x;
  if (idx >= 4*NQ) return;
  int li = idx / NQ, n = idx % NQ;
  const float* src = (li==0)?b0f : (li==1)?b0b : (li==2)?b1f : b1b;
  int ch = n/36, g = (n%36)&3;
  outb[idx] = src[g*HCH + ch];
}

// ---------- x-part GEMM (unchanged from passing round-4 kernel) ----------
__global__ __launch_bounds__(256) void k_gemm(
    const _Float16* __restrict__ A, const _Float16* __restrict__ Bt,
    _Float16* __restrict__ Co, const float* __restrict__ biasArr, int K)
{
  __shared__ _Float16 As[128*32];
  __shared__ _Float16 Bs[128*32];
  int flat = blockIdx.x;
  int cpx  = gridDim.x >> 3;
  int swz  = (flat & 7)*cpx + (flat >> 3);
  int dir  = swz / (64*36);
  int rem  = swz % (64*36);
  size_t m0 = (size_t)(rem / 36) * 128;
  size_t n0 = (size_t)(rem % 36) * 128;
  const _Float16* Bd = Bt + (size_t)dir*NQ*K;
  _Float16*       Cd = Co + (size_t)dir*NROWS*NQ;
  const float* bias  = biasArr + dir*NQ;

  int tid = threadIdx.x;
  int w = tid >> 6, l = tid & 63;
  int wm = w >> 1, wn = w & 1;
  int lr = l & 15, lk = l >> 4;
  int sr = tid >> 2, sc = tid & 3;

  floatx4 acc[4][4] = {};
  for (int kt = 0; kt < K; kt += 32) {
    __syncthreads();
    {
      int r = sr;       int cg = sc ^ ((r>>1)&3);
      gll16(A  + (m0 + r)*K + kt + cg*8, As + r*32 + sc*8);
      r = sr + 64;      cg = sc ^ ((r>>1)&3);
      gll16(A  + (m0 + r)*K + kt + cg*8, As + r*32 + sc*8);
      r = sr;           cg = sc ^ ((r>>1)&3);
      gll16(Bd + (n0 + r)*K + kt + cg*8, Bs + r*32 + sc*8);
      r = sr + 64;      cg = sc ^ ((r>>1)&3);
      gll16(Bd + (n0 + r)*K + kt + cg*8, Bs + r*32 + sc*8);
    }
    __syncthreads();
    half8 a[4], b[4];
    #pragma unroll
    for (int mi=0; mi<4; ++mi){
      int row = wm*64 + mi*16 + lr;
      int sl  = lk ^ ((row>>1)&3);
      a[mi] = *(const half8*)(As + row*32 + sl*8);
    }
    #pragma unroll
    for (int ni=0; ni<4; ++ni){
      int row = wn*64 + ni*16 + lr;
      int sl  = lk ^ ((row>>1)&3);
      b[ni] = *(const half8*)(Bs + row*32 + sl*8);
    }
    #pragma unroll
    for (int mi=0; mi<4; ++mi)
      #pragma unroll
      for (int ni=0; ni<4; ++ni)
        acc[mi][ni] = __builtin_amdgcn_mfma_f32_16x16x32_f16(a[mi], b[ni], acc[mi][ni], 0,0,0);
  }
  #pragma unroll
  for (int mi=0; mi<4; ++mi)
    #pragma unroll
    for (int ni=0; ni<4; ++ni)
      #pragma unroll
      for (int j=0; j<4; ++j) {
        size_t m = m0 + wm*64 + mi*16 + lk*4 + j;
        size_t n = n0 + wn*64 + ni*16 + lr;
        Cd[m*NQ + n] = (_Float16)(acc[mi][ni][j] + bias[n]);
      }
}

// ---------- persistent bidirectional scan: one kernel runs all 128 steps ----------
// 256 blocks = 2 dirs x 128 ch, 1 block/CU (LDS 122,880 B). Wh slice LDS-resident.
// Waves M-split (16 batch rows each, full K) -> no cross-wave reduce.
// Cell state in registers. Grid barrier: sense-reversing, device-scope atomics.
__global__ __launch_bounds__(256) void k_scan(
    const _Float16* __restrict__ Wh,   // [2][4620][1152]
    const _Float16* __restrict__ Zx,   // [2][8192][4608] fp16, bias included
    _Float16* __restrict__ Hb,         // [2 phase][2 dir][64][1152]
    _Float16* __restrict__ HS,         // [2][128][64][1152]
    unsigned* bar)                     // [0]=count, [1]=generation (zeroed by host)
{
  __shared__ _Float16 wlds[48*KH];     // 110,592 B, XOR-swizzled 16B chunks
  __shared__ float red[4][16][48];     // 12,288 B per-wave C scratch
  int bid = blockIdx.x;
  int d = bid >> 7, ch = bid & 127;
  int tid = threadIdx.x, w = tid >> 6, l = tid & 63;
  int lr = l & 15, lk = l >> 4;
  const _Float16* wb  = Wh + (size_t)d*4620*KH + (size_t)(ch*36)*KH;
  const _Float16* zxd = Zx + (size_t)d*NROWS*NQ + ch*36;

  // preload Wh slice into LDS (swizzle: chunk c -> c ^ (row&7); read side mirrors)
  for (int idx = tid; idx < 48*144; idx += 256) {
    int row = idx/144, c = idx%144;
    half8 v = *(const half8*)(wb + (size_t)row*KH + c*8);
    *(half8*)(wlds + (size_t)row*KH + (size_t)((c ^ (row&7))*8)) = v;
  }
  __syncthreads();

  float cst0 = 0.f, cst1 = 0.f, cst2 = 0.f;   // cell state, static slots

  for (int s = 0; s < T_; ++s) {
    int t = d ? (T_-1-s) : s;
    int par = s & 1;
    const _Float16* hin  = Hb + (size_t)(par*2 + d)*B_*KH;
    _Float16*       hout = Hb + (size_t)(((par^1)*2) + d)*B_*KH;
    _Float16*       hsd  = HS + (size_t)((d*T_ + t)*B_)*KH + ch*9;

    // prefetch this step's Zx gate quads (4 f16 = 8B each)
    half4v zp0 = {}, zp1 = {}, zp2 = {};
    {
      int pi = l;        int row = pi/9, p = pi%9;
      zp0 = *(const half4v*)(zxd + (size_t)((w*16+row)*T_ + t)*NQ + p*4);
      pi = l + 64;       row = pi/9; p = pi%9;
      zp1 = *(const half4v*)(zxd + (size_t)((w*16+row)*T_ + t)*NQ + p*4);
      pi = l + 128;
      if (pi < 144) { row = pi/9; p = pi%9;
        zp2 = *(const half4v*)(zxd + (size_t)((w*16+row)*T_ + t)*NQ + p*4); }
    }

    // z = Hin x Wh^T : wave w owns rows w*16..w*16+15, cols 0..47, K=1152
    floatx4 acc[3] = {};
    #pragma unroll 6
    for (int ki = 0; ki < 36; ++ki) {
      half8 a = *(const half8*)(hin + (size_t)(w*16+lr)*KH + ki*32 + lk*8);
      #pragma unroll
      for (int ni = 0; ni < 3; ++ni) {
        int row = ni*16 + lr;
        int cc = (ki*4 + lk) ^ (row & 7);
        half8 b = *(const half8*)(wlds + (size_t)row*KH + cc*8);
        acc[ni] = __builtin_amdgcn_mfma_f32_16x16x32_f16(a, b, acc[ni], 0,0,0);
      }
    }
    #pragma unroll
    for (int ni=0; ni<3; ++ni)
      #pragma unroll
      for (int j=0; j<4; ++j)
        red[w][lk*4+j][ni*16+lr] = acc[ni][j];   // D: col=lane&15, row=(lane>>4)*4+j

    // gate epilogue (wave-local LDS dependency; compiler orders via lgkmcnt)
    #pragma unroll
    for (int ii=0; ii<3; ++ii) {
      int pi = l + ii*64;
      if (pi < 144) {
        int row = pi/9, p = pi%9;
        int brow = w*16 + row;
        floatx4 rv = *(floatx4*)&red[w][row][p*4];
        half4v z = (ii==0)?zp0:((ii==1)?zp1:zp2);
        float zi = (float)z[0] + rv[0];
        float zf = (float)z[1] + rv[1];
        float zo = (float)z[2] + rv[2];
        float zg = (float)z[3] + rv[3];
        float& cc = (ii==0)?cst0:((ii==1)?cst1:cst2);
        float cn = sigm(zf)*cc + sigm(zi)*tanhf(zg);
        float h  = sigm(zo)*tanhf(cn);
        cc = cn;
        _Float16 hh = (_Float16)h;
        hout[(size_t)brow*KH + ch*9 + p] = hh;
        hsd[(size_t)brow*KH + p] = hh;
      }
    }

    // grid barrier: device-scope acq/rel atomics carry the L2 wb/inv for h visibility
    __syncthreads();
    if (tid == 0) {
      unsigned g = __hip_atomic_load(bar+1, __ATOMIC_RELAXED, __HIP_MEMORY_SCOPE_AGENT);
      unsigned old = __hip_atomic_fetch_add(bar, 1u, __ATOMIC_ACQ_REL, __HIP_MEMORY_SCOPE_AGENT);
      if (old == 255u) {
        __hip_atomic_store(bar, 0u, __ATOMIC_RELAXED, __HIP_MEMORY_SCOPE_AGENT);
        __hip_atomic_store(bar+1, g+1u, __ATOMIC_RELEASE, __HIP_MEMORY_SCOPE_AGENT);
      } else {
        int tries = 0;
        while (__hip_atomic_load(bar+1, __ATOMIC_ACQUIRE, __HIP_MEMORY_SCOPE_AGENT) == g) {
          __builtin_amdgcn_s_sleep(2);
          if (++tries > (1<<22)) break;   // deadlock-proof: fails loudly, never hangs
        }
      }
    }
    __syncthreads();
  }
}

// ---------- layer-1 input: A1[(b*T+t)][k] = hs_f + hs_b (fp16) ----------
__global__ void k_pack_A1(const _Float16* __restrict__ hs, _Float16* __restrict__ A1, int nchunks){
  int i = blockIdx.x*256 + threadIdx.x;
  if (i >= nchunks) return;
  int r  = i / (KH/8);
  int kc = i % (KH/8);
  int b = r / T_, t = r % T_;
  half8 xv = ((const half8*)(hs + (size_t)(t*B_ + b)*KH))[kc];
  half8 yv = ((const half8*)(hs + (size_t)((T_ + t)*B_ + b)*KH))[kc];
  half8 o;
  #pragma unroll
  for (int e=0; e<8; ++e) o[e] = (_Float16)((float)xv[e] + (float)yv[e]);
  ((half8*)A1)[i] = o;
}

// ---------- final FC ----------
__global__ __launch_bounds__(64) void k_fc(const _Float16* __restrict__ hs,
                                           const float* __restrict__ fw,
                                           const float* __restrict__ fb,
                                           float* __restrict__ out){
  int r = blockIdx.x;
  int b = r / T_, t = r % T_;
  int l = threadIdx.x;
  const _Float16* ha = hs + (size_t)(t*B_ + b)*KH;
  const _Float16* hc = hs + (size_t)((T_ + t)*B_ + b)*KH;
  float accv[7] = {0,0,0,0,0,0,0};
  for (int k=l; k<KH; k+=64){
    float h = (float)ha[k] + (float)hc[k];
    #pragma unroll
    for (int nc=0; nc<7; ++nc) accv[nc] += h * fw[nc*KH + k];
  }
  #pragma unroll
  for (int nc=0; nc<7; ++nc){
    float v = accv[nc];
    for (int off=32; off; off>>=1) v += __shfl_down(v, off, 64);
    if (l==0) out[(size_t)r*7 + nc] = v + fb[nc];
  }
}

extern "C" void kernel_launch(void* const* d_in, const int* in_sizes, int n_in,
                              void* d_out, int out_size, void* d_ws, size_t ws_size,
                              hipStream_t stream)
{
  const float* x    = (const float*)d_in[0];
  const float* w_f0 = (const float*)d_in[1];
  const float* b_f0 = (const float*)d_in[2];
  const float* w_b0 = (const float*)d_in[3];
  const float* b_b0 = (const float*)d_in[4];
  const float* w_f1 = (const float*)d_in[5];
  const float* b_f1 = (const float*)d_in[6];
  const float* w_b1 = (const float*)d_in[7];
  const float* b_b1 = (const float*)d_in[8];
  const float* fc_w = (const float*)d_in[9];
  const float* fc_b = (const float*)d_in[10];
  float* out = (float*)d_out;

  // ---- workspace arena (244.25 MiB, live-range aliased; layout as round 4) ----
  char* base = (char*)d_ws;
  const size_t TOTAL = 256112640;
  if (ws_size < TOTAL) {
    (void)hipMemsetAsync(d_out, 0x7F, (size_t)out_size*4, stream);
    return;
  }
  _Float16* A0   = (_Float16*)(base);
  _Float16* A1   = (_Float16*)(base);                     // alias (A0 dead)
  _Float16* WxT1 = (_Float16*)(base + 18874368);          // alias (A0 dead)
  _Float16* WxT0 = (_Float16*)(base + 40108032);
  _Float16* hs0  = (_Float16*)(base + 40108032);          // alias (WxT0 dead)
  _Float16* hs1  = (_Float16*)(base + 40108032);          // alias (hs0 dead)
  _Float16* Zx   = (_Float16*)(base + 82575360);
  _Float16* WhT0 = (_Float16*)(base + 233570304);
  _Float16* WhT1 = (_Float16*)(base + 233570304);         // alias (WhT0 dead)
  float*    biasn= (float*)   (base + 254859264);
  _Float16* Hb   = (_Float16*)(base + 254932992);
  unsigned* bar  = (unsigned*)(base + 255522816);         // grid-barrier state

  int tot0 = NQ*2304 + 4620*KH;
  int tot1 = NQ*1152 + 4620*KH;

  // ---- packs (layer 0) ----
  k_cast_f16<<<18874368/4/256, 256, 0, stream>>>(x, A0, 18874368/4);
  k_pack_w2<<<(tot0+255)/256,256,0,stream>>>(w_f0, WxT0,                   WhT0,           256, tot0);
  k_pack_w2<<<(tot0+255)/256,256,0,stream>>>(w_b0, WxT0 + (size_t)NQ*2304, WhT0 + 4620*KH, 256, tot0);
  k_pack_bias<<<(4*NQ+255)/256,256,0,stream>>>(b_f0,b_b0,b_f1,b_b1, biasn);

  // ---- layer 0 ----
  (void)hipMemsetAsync(Hb, 0, 589824, stream);
  (void)hipMemsetAsync(bar, 0, 16, stream);
  k_gemm<<<4608, 256, 0, stream>>>(A0, WxT0, Zx, biasn, 2304);
  k_scan<<<256, 256, 0, stream>>>(WhT0, Zx, Hb, hs0, bar);

  // ---- layer 1 packs (WhT0/A0 dead) ----
  k_pack_w2<<<(tot1+255)/256,256,0,stream>>>(w_f1, WxT1,                   WhT1,           128, tot1);
  k_pack_w2<<<(tot1+255)/256,256,0,stream>>>(w_b1, WxT1 + (size_t)NQ*1152, WhT1 + 4620*KH, 128, tot1);
  k_pack_A1<<<(NROWS*KH/8+255)/256,256,0,stream>>>(hs0, A1, NROWS*KH/8);

  // ---- layer 1 ----
  (void)hipMemsetAsync(Hb, 0, 589824, stream);
  (void)hipMemsetAsync(bar, 0, 16, stream);
  k_gemm<<<4608, 256, 0, stream>>>(A1, WxT1, Zx, biasn + 2*NQ, 1152);
  k_scan<<<256, 256, 0, stream>>>(WhT1, Zx, Hb, hs1, bar);

  // ---- FC ----
  k_fc<<<NROWS, 64, 0, stream>>>(hs1, fc_w, fc_b, out);
}